// Round 1
// 586.663 us; speedup vs baseline: 1.0235x; 1.0235x over previous
//
#include <hip/hip_runtime.h>

// Problem constants (from reference):
// N=50000, C_IN=256, D=25000, K=16, C_OUT=256
// y[d,k,:] = (x[n]*symm_norm[n]) @ (w[:256]+w[256:]) + b, n = domains[d,k]
// => z[n,:] = xs[n,:] @ weff + b  (GEMM, [50000,256]x[256,256])
//    y[r,:] = z[domains[r],:]     (gather, 400000 rows)

#define GM 50000
#define GK 256
#define GN 256
#define BM 128
#define BN 128
#define BK 16
#define LDA (BM + 4)   // pad keeps 16B alignment: 132 floats = 33*16B
#define LDB (BN + 4)

// Register-blocked fp32 GEMM: 128x128 block tile, 256 threads, 8x8 micro-tile
// per thread (2x2 quadrants of float4). As stored TRANSPOSED [BK][BM] so the
// inner loop is 4 x ds_read_b128 per 64 FMAs (vs 8 scalar reads per 16 FMAs
// in the previous version -> that kernel was LDS-issue-bound).
__global__ __launch_bounds__(256, 4)
void gemm_z_kernel(const float* __restrict__ x,
                   const float* __restrict__ sn,
                   const float* __restrict__ w,
                   const float* __restrict__ b,
                   float* __restrict__ z) {
    __shared__ float As[BK][LDA];
    __shared__ float Bs[BK][LDB];

    const int t  = threadIdx.x;
    const int tx = t & 15;             // 16 thread-cols
    const int ty = t >> 4;             // 16 thread-rows
    const int rowBase = blockIdx.x * BM;
    const int colBase = blockIdx.y * BN;

    // A staging: each thread loads 2x float4 along k (coalesced 16-float rows)
    const int a_m = t >> 2;            // 0..63 (+64 on 2nd pass)
    const int a_k = (t & 3) * 4;       // 0,4,8,12
    // B staging: 32 threads cover a 128-wide row; 8 k-rows per pass
    const int b_k = t >> 5;            // 0..7 (+8 on 2nd pass)
    const int b_n = (t & 31) * 4;      // 0..124

    float acc[8][8] = {};

    for (int k0 = 0; k0 < GK; k0 += BK) {
        // --- stage A (transposed, scaled by symm_norm) ---
        #pragma unroll
        for (int h = 0; h < 2; ++h) {
            const int mr = a_m + h * 64;
            const int m  = rowBase + mr;
            float4 v = make_float4(0.f, 0.f, 0.f, 0.f);
            if (m < GM) {
                v = *reinterpret_cast<const float4*>(&x[(size_t)m * GK + k0 + a_k]);
                const float s = sn[m];
                v.x *= s; v.y *= s; v.z *= s; v.w *= s;
            }
            As[a_k + 0][mr] = v.x;
            As[a_k + 1][mr] = v.y;
            As[a_k + 2][mr] = v.z;
            As[a_k + 3][mr] = v.w;
        }
        // --- stage B: weff = w_top + w_bot ---
        #pragma unroll
        for (int h = 0; h < 2; ++h) {
            const int kk = b_k + h * 8;
            const int gk = k0 + kk;
            const int gn = colBase + b_n;
            float4 v0 = *reinterpret_cast<const float4*>(&w[(size_t)gk * GN + gn]);
            float4 v1 = *reinterpret_cast<const float4*>(&w[(size_t)(gk + 256) * GN + gn]);
            v0.x += v1.x; v0.y += v1.y; v0.z += v1.z; v0.w += v1.w;
            *reinterpret_cast<float4*>(&Bs[kk][b_n]) = v0;
        }
        __syncthreads();

        #pragma unroll
        for (int kk = 0; kk < BK; ++kk) {
            float a[8], bb[8];
            *reinterpret_cast<float4*>(&a[0])  =
                *reinterpret_cast<const float4*>(&As[kk][ty * 4]);
            *reinterpret_cast<float4*>(&a[4])  =
                *reinterpret_cast<const float4*>(&As[kk][64 + ty * 4]);
            *reinterpret_cast<float4*>(&bb[0]) =
                *reinterpret_cast<const float4*>(&Bs[kk][tx * 4]);
            *reinterpret_cast<float4*>(&bb[4]) =
                *reinterpret_cast<const float4*>(&Bs[kk][64 + tx * 4]);
            #pragma unroll
            for (int i = 0; i < 8; ++i)
                #pragma unroll
                for (int j = 0; j < 8; ++j)
                    acc[i][j] += a[i] * bb[j];
        }
        __syncthreads();
    }

    // epilogue: add bias, float4 stores (2 per output row)
    const int n0 = colBase + tx * 4;
    const float4 bias0 = *reinterpret_cast<const float4*>(&b[n0]);
    const float4 bias1 = *reinterpret_cast<const float4*>(&b[n0 + 64]);
    #pragma unroll
    for (int i = 0; i < 8; ++i) {
        const int m = rowBase + (i >> 2) * 64 + ty * 4 + (i & 3);
        if (m >= GM) continue;
        float* zr = &z[(size_t)m * GN];
        float4 v;
        v.x = acc[i][0] + bias0.x; v.y = acc[i][1] + bias0.y;
        v.z = acc[i][2] + bias0.z; v.w = acc[i][3] + bias0.w;
        *reinterpret_cast<float4*>(&zr[n0]) = v;
        v.x = acc[i][4] + bias1.x; v.y = acc[i][5] + bias1.y;
        v.z = acc[i][6] + bias1.z; v.w = acc[i][7] + bias1.w;
        *reinterpret_cast<float4*>(&zr[n0 + 64]) = v;
    }
}

// Gather: out[r, :] = z[domains[r], :]. One wave per output row (1 KB),
// 4 rows per 256-thread block, float4 per lane -> fully coalesced 1 KB
// reads and writes.
__global__ __launch_bounds__(256)
void gather_kernel(const float* __restrict__ z,
                   const int* __restrict__ domains,
                   float* __restrict__ out,
                   int R) {
    const int r = blockIdx.x * 4 + (threadIdx.x >> 6);
    if (r >= R) return;
    const int c = (threadIdx.x & 63) * 4;
    const int n = domains[r];
    const float4 v = *reinterpret_cast<const float4*>(&z[(size_t)n * GN + c]);
    *reinterpret_cast<float4*>(&out[(size_t)r * GN + c]) = v;
}

extern "C" void kernel_launch(void* const* d_in, const int* in_sizes, int n_in,
                              void* d_out, int out_size, void* d_ws, size_t ws_size,
                              hipStream_t stream) {
    const float* x  = (const float*)d_in[0];   // [50000, 256]
    const float* sn = (const float*)d_in[1];   // [50000]
    const int*   dm = (const int*)d_in[2];     // [25000, 16] (int32 per harness)
    const float* w  = (const float*)d_in[3];   // [512, 256]
    const float* b  = (const float*)d_in[4];   // [256]
    float* out = (float*)d_out;                // [25000, 16, 256]
    float* z   = (float*)d_ws;                 // [50000, 256] scratch (51.2 MB)

    dim3 gemm_grid((GM + BM - 1) / BM, GN / BN);   // (391, 2)
    gemm_z_kernel<<<gemm_grid, 256, 0, stream>>>(x, sn, w, b, z);

    const int R = 25000 * 16;                      // 400000 output rows
    gather_kernel<<<(R + 3) / 4, 256, 0, stream>>>(z, dm, out, R);
}

// Round 4
// 539.667 us; speedup vs baseline: 1.1127x; 1.0871x over previous
//
#include <hip/hip_runtime.h>

// Problem: y[d,k,:] = (x[n]*sn[n]) @ (w[:256]+w[256:]) + b, n = domains[d,k]
// Strategy: invert the gather. Build node->output-row buckets, then the GEMM
// epilogue scatters each z-row directly to all duplicate output rows.
// Removes the z round-trip (51 MB write + 409.6 MB random re-read) and the
// separate gather kernel entirely.

#define GM 50000
#define GK 256
#define GN 256
#define RTOT 400000      // 25000 * 16 output rows
#define BM 128
#define BN 128
#define BK 16
#define LDA (BM + 4)     // pad keeps 16B alignment: 132 floats = 33*16B
#define LDB (BN + 4)
#define CAP 64           // max dup-count per node; Poisson(8) max over 50K ~ 30
#define OVF_MAX 4096

typedef float v4f __attribute__((ext_vector_type(4)));  // nontemporal-compatible

__global__ __launch_bounds__(256)
void zero_kernel(int* __restrict__ cnt, int* __restrict__ ovf_cnt) {
    const int i = blockIdx.x * 256 + threadIdx.x;
    if (i < GM) cnt[i] = 0;
    if (i == 0) *ovf_cnt = 0;
}

// Inverse index: bucket[n*CAP + j] = output rows r with domains[r]==n.
__global__ __launch_bounds__(256)
void build_kernel(const int* __restrict__ dm, int* __restrict__ cnt,
                  int* __restrict__ bucket, int* __restrict__ ovf,
                  int* __restrict__ ovf_cnt) {
    const int r = blockIdx.x * 256 + threadIdx.x;
    if (r >= RTOT) return;
    const int n = dm[r];
    const int slot = atomicAdd(&cnt[n], 1);
    if (slot < CAP) {
        bucket[n * CAP + slot] = r;
    } else {
        const int o = atomicAdd(ovf_cnt, 1);
        if (o < OVF_MAX) ovf[o] = r;
    }
}

// Register-blocked fp32 GEMM (128x128 tile, 256 thr, 8x8 micro-tile) with
// scatter epilogue: each computed row is written to every duplicate output
// row via the bucket list. z is only written for overflowed nodes (never, in
// practice) so the common path writes exactly the 409.6 MB output.
__global__ __launch_bounds__(256, 4)
void gemm_scatter_kernel(const float* __restrict__ x,
                         const float* __restrict__ sn,
                         const float* __restrict__ w,
                         const float* __restrict__ b,
                         const int* __restrict__ cnt,
                         const int* __restrict__ bucket,
                         float* __restrict__ out,
                         float* __restrict__ z) {
    __shared__ float As[BK][LDA];   // transposed: b128 reads in inner loop
    __shared__ float Bs[BK][LDB];

    const int t  = threadIdx.x;
    const int tx = t & 15;
    const int ty = t >> 4;
    const int rowBase = blockIdx.x * BM;
    const int colBase = blockIdx.y * BN;

    const int a_m = t >> 2;            // 0..63 (+64 on 2nd pass)
    const int a_k = (t & 3) * 4;       // 0,4,8,12
    const int b_k = t >> 5;            // 0..7 (+8 on 2nd pass)
    const int b_n = (t & 31) * 4;      // 0..124

    float acc[8][8] = {};

    for (int k0 = 0; k0 < GK; k0 += BK) {
        #pragma unroll
        for (int h = 0; h < 2; ++h) {
            const int mr = a_m + h * 64;
            const int m  = rowBase + mr;
            float4 v = make_float4(0.f, 0.f, 0.f, 0.f);
            if (m < GM) {
                v = *reinterpret_cast<const float4*>(&x[(size_t)m * GK + k0 + a_k]);
                const float s = sn[m];
                v.x *= s; v.y *= s; v.z *= s; v.w *= s;
            }
            As[a_k + 0][mr] = v.x;
            As[a_k + 1][mr] = v.y;
            As[a_k + 2][mr] = v.z;
            As[a_k + 3][mr] = v.w;
        }
        #pragma unroll
        for (int h = 0; h < 2; ++h) {
            const int kk = b_k + h * 8;
            const int gk = k0 + kk;
            const int gn = colBase + b_n;
            float4 v0 = *reinterpret_cast<const float4*>(&w[(size_t)gk * GN + gn]);
            float4 v1 = *reinterpret_cast<const float4*>(&w[(size_t)(gk + 256) * GN + gn]);
            v0.x += v1.x; v0.y += v1.y; v0.z += v1.z; v0.w += v1.w;
            *reinterpret_cast<float4*>(&Bs[kk][b_n]) = v0;
        }
        __syncthreads();

        #pragma unroll
        for (int kk = 0; kk < BK; ++kk) {
            float a[8], bb[8];
            *reinterpret_cast<float4*>(&a[0])  =
                *reinterpret_cast<const float4*>(&As[kk][ty * 4]);
            *reinterpret_cast<float4*>(&a[4])  =
                *reinterpret_cast<const float4*>(&As[kk][64 + ty * 4]);
            *reinterpret_cast<float4*>(&bb[0]) =
                *reinterpret_cast<const float4*>(&Bs[kk][tx * 4]);
            *reinterpret_cast<float4*>(&bb[4]) =
                *reinterpret_cast<const float4*>(&Bs[kk][64 + tx * 4]);
            #pragma unroll
            for (int i = 0; i < 8; ++i)
                #pragma unroll
                for (int j = 0; j < 8; ++j)
                    acc[i][j] += a[i] * bb[j];
        }
        __syncthreads();
    }

    // Scatter epilogue: bias, then write this row's two float4 spans to every
    // duplicate output row. 16 tx-threads cover 128 contiguous cols -> 512B
    // contiguous stores per row-half; out is write-once -> nontemporal.
    const int n0 = colBase + tx * 4;
    const float4 bias0 = *reinterpret_cast<const float4*>(&b[n0]);
    const float4 bias1 = *reinterpret_cast<const float4*>(&b[n0 + 64]);
    #pragma unroll
    for (int i = 0; i < 8; ++i) {
        const int m = rowBase + (i >> 2) * 64 + ty * 4 + (i & 3);
        if (m >= GM) continue;
        v4f v0, v1;
        v0.x = acc[i][0] + bias0.x; v0.y = acc[i][1] + bias0.y;
        v0.z = acc[i][2] + bias0.z; v0.w = acc[i][3] + bias0.w;
        v1.x = acc[i][4] + bias1.x; v1.y = acc[i][5] + bias1.y;
        v1.z = acc[i][6] + bias1.z; v1.w = acc[i][7] + bias1.w;
        const int c  = cnt[m];
        const int cc = c < CAP ? c : CAP;
        const int* bk = &bucket[m * CAP];
        for (int j = 0; j < cc; ++j) {
            const int r = bk[j];
            float* orow = &out[(size_t)r * GN];
            __builtin_nontemporal_store(v0, reinterpret_cast<v4f*>(&orow[n0]));
            __builtin_nontemporal_store(v1, reinterpret_cast<v4f*>(&orow[n0 + 64]));
        }
        if (c > CAP) {   // overflow escape hatch: stash z-row for cleanup
            float* zr = &z[(size_t)m * GN];
            *reinterpret_cast<v4f*>(&zr[n0])      = v0;
            *reinterpret_cast<v4f*>(&zr[n0 + 64]) = v1;
        }
    }
}

// Handles bucket-overflow rows (empty in practice): out[r] = z[dm[r]].
__global__ __launch_bounds__(256)
void cleanup_kernel(const float* __restrict__ z, const int* __restrict__ dm,
                    const int* __restrict__ ovf, const int* __restrict__ ovf_cnt,
                    float* __restrict__ out) {
    int nov = *ovf_cnt;
    if (nov > OVF_MAX) nov = OVF_MAX;
    const int lane = threadIdx.x & 63;
    const int wid  = (blockIdx.x * 256 + threadIdx.x) >> 6;
    const int nw   = (gridDim.x * 256) >> 6;
    for (int i = wid; i < nov; i += nw) {
        const int r = ovf[i];
        const int n = dm[r];
        const float4 v = *reinterpret_cast<const float4*>(&z[(size_t)n * GN + lane * 4]);
        *reinterpret_cast<float4*>(&out[(size_t)r * GN + lane * 4]) = v;
    }
}

extern "C" void kernel_launch(void* const* d_in, const int* in_sizes, int n_in,
                              void* d_out, int out_size, void* d_ws, size_t ws_size,
                              hipStream_t stream) {
    const float* x  = (const float*)d_in[0];   // [50000, 256]
    const float* sn = (const float*)d_in[1];   // [50000]
    const int*   dm = (const int*)d_in[2];     // [25000, 16] (int32 per harness)
    const float* w  = (const float*)d_in[3];   // [512, 256]
    const float* b  = (const float*)d_in[4];   // [256]
    float* out = (float*)d_out;                // [25000, 16, 256]

    // Workspace layout (~64.2 MB total)
    char* ws = (char*)d_ws;
    float* z      = (float*)ws;                          // 51,200,000 B
    int*   cnt    = (int*)(ws + 51200000);               // 200,000 B
    int*   bucket = cnt + GM;                            // 12,800,000 B
    int*   ovf_cnt= bucket + (size_t)GM * CAP;           // 4 B
    int*   ovf    = ovf_cnt + 4;                         // 16,384 B

    zero_kernel<<<(GM + 255) / 256, 256, 0, stream>>>(cnt, ovf_cnt);
    build_kernel<<<(RTOT + 255) / 256, 256, 0, stream>>>(dm, cnt, bucket, ovf, ovf_cnt);

    dim3 gemm_grid((GM + BM - 1) / BM, GN / BN);         // (391, 2)
    gemm_scatter_kernel<<<gemm_grid, 256, 0, stream>>>(x, sn, w, b, cnt, bucket, out, z);

    cleanup_kernel<<<64, 256, 0, stream>>>(z, dm, ovf, ovf_cnt, out);
}